// Round 1
// baseline (307.263 us; speedup 1.0000x reference)
//
#include <hip/hip_runtime.h>

// ForgetMult: h_t = f_t*x_t + (1-f_t)*h_{t-1}, scan over T, independent per (b,h) channel.
// Layout [T, B, H] row-major: element (t, c) at t*BH + c, c = b*H+h in [0, BH).
// One thread per channel; coalesced across lanes at every t; UNROLL-deep register
// staging so loads stream ahead of the serial h-chain.

constexpr int UNROLL = 16;

__global__ __launch_bounds__(64) void forgetmult_kernel(
    const float* __restrict__ f, const float* __restrict__ x,
    const float* __restrict__ h0, float* __restrict__ out,
    int T, int BH)
{
    const int c = blockIdx.x * 64 + threadIdx.x;
    if (c >= BH) return;

    float h = h0[c];
    const float* fp = f + c;
    const float* xp = x + c;
    float*       op = out + c;
    const size_t stride = (size_t)BH;

    for (int t0 = 0; t0 < T; t0 += UNROLL) {
        float fv[UNROLL], xv[UNROLL];
        #pragma unroll
        for (int u = 0; u < UNROLL; ++u) {
            const size_t off = (size_t)(t0 + u) * stride;
            fv[u] = fp[off];
            xv[u] = xp[off];
        }
        #pragma unroll
        for (int u = 0; u < UNROLL; ++u) {
            // h = f*x + (1-f)*h  ==  h + f*(x-h)
            h = fmaf(fv[u], xv[u] - h, h);
            op[(size_t)(t0 + u) * stride] = h;
        }
    }
}

extern "C" void kernel_launch(void* const* d_in, const int* in_sizes, int n_in,
                              void* d_out, int out_size, void* d_ws, size_t ws_size,
                              hipStream_t stream) {
    const float* f  = (const float*)d_in[0];
    const float* x  = (const float*)d_in[1];
    const float* h0 = (const float*)d_in[2];
    float* out = (float*)d_out;

    const int BH = in_sizes[2];          // B*H from hidden_init
    const int T  = in_sizes[0] / BH;     // 1024

    const int block = 64;
    const int grid  = (BH + block - 1) / block;
    forgetmult_kernel<<<grid, block, 0, stream>>>(f, x, h0, out, T, BH);
}

// Round 2
// 294.001 us; speedup vs baseline: 1.0451x; 1.0451x over previous
//
#include <hip/hip_runtime.h>

// ForgetMult: h_t = f_t*x_t + (1-f_t)*h_{t-1} per channel c = b*H+h, scan over T.
// Layout [T, B, H]: element (t, c) at t*BH + c. One thread per channel (BH=32768
// -> 512 waves, ~2/CU; grid-limited occupancy). The serial h-chain is cheap VALU;
// the game is memory-level parallelism: two named register buffers (A/B) of
// U=16 (f,x) pairs each, pipelined so ~32 loads stay in flight per wave while
// the other buffer computes. __launch_bounds__(64,1) frees the register
// allocator to keep all staged values live (round-1 failure: VGPR=32 -> MLP~8).

constexpr int U = 16;

__global__ __launch_bounds__(64, 1) void forgetmult_kernel(
    const float* __restrict__ f, const float* __restrict__ x,
    const float* __restrict__ h0, float* __restrict__ out,
    int T, int BH)
{
    const int c = blockIdx.x * 64 + threadIdx.x;
    if (c >= BH) return;

    const size_t stride = (size_t)BH;
    const float* fp = f + c;
    const float* xp = x + c;
    float*       op = out + c;

    float h = h0[c];

    float fA[U], xA[U], fB[U], xB[U];

    const int nblk = T / (2 * U);   // full double-blocks (T=1024, U=16 -> 16)
    int t = 0;

    if (nblk > 0) {
        // prologue: fill buffer A @ t=0
        #pragma unroll
        for (int u = 0; u < U; ++u) {
            const size_t off = (size_t)u * stride;
            fA[u] = __builtin_nontemporal_load(fp + off);
            xA[u] = __builtin_nontemporal_load(xp + off);
        }
        for (int b = 0; b < nblk; ++b) {
            // issue B's loads @ t+U (32 loads in flight over A's compute)
            #pragma unroll
            for (int u = 0; u < U; ++u) {
                const size_t off = (size_t)(t + U + u) * stride;
                fB[u] = __builtin_nontemporal_load(fp + off);
                xB[u] = __builtin_nontemporal_load(xp + off);
            }
            // compute + store A @ t
            #pragma unroll
            for (int u = 0; u < U; ++u) {
                h = fmaf(fA[u], xA[u] - h, h);   // f*x + (1-f)*h
                __builtin_nontemporal_store(h, op + (size_t)(t + u) * stride);
            }
            // issue A's loads @ t+2U (keeps pipeline primed over B's compute)
            if (b + 1 < nblk) {
                #pragma unroll
                for (int u = 0; u < U; ++u) {
                    const size_t off = (size_t)(t + 2 * U + u) * stride;
                    fA[u] = __builtin_nontemporal_load(fp + off);
                    xA[u] = __builtin_nontemporal_load(xp + off);
                }
            }
            // compute + store B @ t+U
            #pragma unroll
            for (int u = 0; u < U; ++u) {
                h = fmaf(fB[u], xB[u] - h, h);
                __builtin_nontemporal_store(h, op + (size_t)(t + U + u) * stride);
            }
            t += 2 * U;
        }
    }

    // scalar tail for T not a multiple of 2U (T=1024: empty)
    for (; t < T; ++t) {
        const float fv = fp[(size_t)t * stride];
        const float xv = xp[(size_t)t * stride];
        h = fmaf(fv, xv - h, h);
        op[(size_t)t * stride] = h;
    }
}

extern "C" void kernel_launch(void* const* d_in, const int* in_sizes, int n_in,
                              void* d_out, int out_size, void* d_ws, size_t ws_size,
                              hipStream_t stream) {
    const float* f  = (const float*)d_in[0];
    const float* x  = (const float*)d_in[1];
    const float* h0 = (const float*)d_in[2];
    float* out = (float*)d_out;

    const int BH = in_sizes[2];          // B*H from hidden_init
    const int T  = in_sizes[0] / BH;     // 1024

    const int block = 64;
    const int grid  = (BH + block - 1) / block;
    forgetmult_kernel<<<grid, block, 0, stream>>>(f, x, h0, out, T, BH);
}